// Round 2
// baseline (296.998 us; speedup 1.0000x reference)
//
#include <hip/hip_runtime.h>
#include <hip/hip_bf16.h>

// SoftmaxLossRScore: mean(relu(logsumexp(A @ Neg^T, axis=1) - rowdot(A,P) + r + 1))
// B=2048, N=32768, D=128. bf16 MFMA fused GEMM+sumexp, no [B,N] materialization.
// A pre-scaled by log2(e) so epilogue is a bare v_exp_f32 (exp2).
// R2: XOR-swizzled LDS for A staging (kills bank conflicts on frag reads).
// R4: B direct global->register (frags are contiguous 64B/row: perfectly
//     coalescible, L2/L3-resident) -- no B LDS, no main-loop barriers, waves
//     fully independent after A preload. Grid 1024 (16 rowTiles x 64 chunks),
//     XCD-swizzled so each XCD owns a 1MB B slice (L2-resident). Reverted
//     R3's setprio/STEP pinning and last-block fold (post-mortem: regression).

#define B_ROWS 2048
#define N_NEG  32768
#define DIM    128
#define LOG2E  1.4426950408889634f
#define LN2    0.6931471805599453f

typedef __bf16 bf16x8 __attribute__((ext_vector_type(8)));
typedef float  f32x4  __attribute__((ext_vector_type(4)));

static __device__ inline unsigned short f2bf(float f) {
    union { float f; unsigned u; } v; v.f = f;
    unsigned r = v.u + 0x7FFF + ((v.u >> 16) & 1);   // round-to-nearest-even
    return (unsigned short)(r >> 16);
}

static __device__ inline void load_lds16(const void* g, void* s) {
    __builtin_amdgcn_global_load_lds(
        (const __attribute__((address_space(1))) void*)g,
        (__attribute__((address_space(3))) void*)s,
        16, 0, 0);
}

// ---------- P1 (merged): anchor->bf16*log2e + pos_sim + zero sumexp, neg->bf16
__global__ void prep(const float* __restrict__ anchor,
                     const float* __restrict__ positive,
                     const float* __restrict__ neg,
                     unsigned short* __restrict__ a_bf,
                     unsigned short* __restrict__ n_bf,
                     float* __restrict__ pos_sim,
                     float* __restrict__ sumexp) {
    int t = threadIdx.x;
    if (blockIdx.x < 256) {
        int row = blockIdx.x * 8 + (t >> 5);
        int c4  = (t & 31) * 4;
        const float4 a4 = *(const float4*)(anchor   + row * DIM + c4);
        const float4 p4 = *(const float4*)(positive + row * DIM + c4);
        float dot = a4.x * p4.x + a4.y * p4.y + a4.z * p4.z + a4.w * p4.w;
        ushort4 ab;
        ab.x = f2bf(a4.x * LOG2E); ab.y = f2bf(a4.y * LOG2E);
        ab.z = f2bf(a4.z * LOG2E); ab.w = f2bf(a4.w * LOG2E);
        *(ushort4*)(a_bf + row * DIM + c4) = ab;
        #pragma unroll
        for (int m = 1; m <= 16; m <<= 1) dot += __shfl_xor(dot, m, 64);
        if ((t & 31) == 0) { pos_sim[row] = dot; sumexp[row] = 0.0f; }
    } else {
        int i = (blockIdx.x - 256) * 256 + t;   // float4 index
        #pragma unroll
        for (int k = 0; k < 4; k++) {
            int idx = i + k * (1024 * 256);
            float4 v = *(const float4*)(neg + (size_t)idx * 4);
            ushort4 o;
            o.x = f2bf(v.x); o.y = f2bf(v.y); o.z = f2bf(v.z); o.w = f2bf(v.w);
            *(ushort4*)(n_bf + (size_t)idx * 4) = o;
        }
    }
}

// ---------- main: fused bf16 GEMM + sum(exp2), B register-direct -------------
// Grid 1024 = 16 row-tiles x 64 chunks (512 cols). Block 256 thr = 4 waves
// (2 row x 2 col). Wave tile: 64 A-rows x 256 cols, walked as 16 j-tiles of
// 16 cols. A-frags register-resident (preloaded via swizzled LDS staging,
// one barrier total). B-frags double-buffered straight from global: for
// frag k, lane (q,c) reads neg row n0+c, bytes [k*64, k*64+64) -- 16 fully
// consumed 64B lines per load. No LDS, no barriers, no lockstep in main loop.
__global__ __launch_bounds__(256, 3) void fused_gemm_lse(
        const unsigned short* __restrict__ A,
        const unsigned short* __restrict__ Nb,
        float* __restrict__ sumexp) {
    __shared__ unsigned short ldsA[128 * 128];   // 32 KB, A staging only

    // XCD-bijective swizzle: xcd = bid&7 owns chunks [xcd*8, xcd*8+8)
    // (1 MB of B -> per-XCD-L2-resident). Consecutive slots share a chunk.
    const int bid  = blockIdx.x;
    const int xcd  = bid & 7;
    const int slot = bid >> 3;              // 0..127
    const int rowTile = slot & 15;
    const int chunk   = xcd * 8 + (slot >> 4);   // 0..63, 512 cols each

    const int wave = threadIdx.x >> 6, lane = threadIdx.x & 63;
    const int wr = wave >> 1, wc = wave & 1;
    const int q = lane >> 4, c = lane & 15;
    const int lrow = lane >> 4;       // staging: row within 4-row group
    const int lchk = lane & 15;       // staging: 16B chunk within row

    const unsigned short* Ag = A + rowTile * (128 * DIM);

    // stage A tile -> LDS (swizzled global source: chunk j of row r at j^(r&7))
    #pragma unroll
    for (int i = 0; i < 8; i++) {
        int off = wave * 4096 + i * 512;            // ushort offset, 4 rows
        int r   = (off >> 7) + lrow;                // absolute row in tile
        int gofs = r * DIM + ((lchk ^ (r & 7)) << 3);
        load_lds16(Ag + gofs, &ldsA[off]);
    }
    asm volatile("s_waitcnt vmcnt(0)" ::: "memory");
    __syncthreads();

    // swizzled k-step chunk offsets (ushort units)
    int swz[4];
    #pragma unroll
    for (int k = 0; k < 4; k++) swz[k] = (((k * 4 + q) ^ (c & 7)) << 3);

    // preload A fragments: wave rows wr*64..+64, 4 subtiles x 4 k-steps
    bf16x8 af[4][4];
    #pragma unroll
    for (int i = 0; i < 4; i++) {
        int row = wr * 64 + i * 16 + c;
        #pragma unroll
        for (int k = 0; k < 4; k++)
            af[i][k] = *(const bf16x8*)&ldsA[row * DIM + swz[k]];
    }
    // LDS done. No further barriers; waves are independent from here on.

    const f32x4 zero4 = {0.f, 0.f, 0.f, 0.f};
    f32x4 sumacc[4] = {zero4, zero4, zero4, zero4};

    // per-lane B base: neg row n0 + c, k-chunk q. Frag k at +k*32 ushorts.
    const unsigned short* bp =
        Nb + ((size_t)(chunk * 512 + wc * 256) + c) * DIM + q * 8;

    bf16x8 bf[2][4];
    #pragma unroll
    for (int k = 0; k < 4; k++)
        bf[0][k] = *(const bf16x8*)(bp + k * 32);

    #pragma unroll
    for (int j = 0; j < 16; j++) {          // 16 cols per j-tile
        if (j + 1 < 16) {                   // prefetch next frags (dbuf regs)
            const unsigned short* bn = bp + (j + 1) * (16 * DIM);
            #pragma unroll
            for (int k = 0; k < 4; k++)
                bf[(j + 1) & 1][k] = *(const bf16x8*)(bn + k * 32);
        }
        f32x4 acc0 = __builtin_amdgcn_mfma_f32_16x16x32_bf16(af[0][0], bf[j & 1][0], zero4, 0, 0, 0);
        f32x4 acc1 = __builtin_amdgcn_mfma_f32_16x16x32_bf16(af[1][0], bf[j & 1][0], zero4, 0, 0, 0);
        f32x4 acc2 = __builtin_amdgcn_mfma_f32_16x16x32_bf16(af[2][0], bf[j & 1][0], zero4, 0, 0, 0);
        f32x4 acc3 = __builtin_amdgcn_mfma_f32_16x16x32_bf16(af[3][0], bf[j & 1][0], zero4, 0, 0, 0);
        #pragma unroll
        for (int k = 1; k < 4; k++) {
            acc0 = __builtin_amdgcn_mfma_f32_16x16x32_bf16(af[0][k], bf[j & 1][k], acc0, 0, 0, 0);
            acc1 = __builtin_amdgcn_mfma_f32_16x16x32_bf16(af[1][k], bf[j & 1][k], acc1, 0, 0, 0);
            acc2 = __builtin_amdgcn_mfma_f32_16x16x32_bf16(af[2][k], bf[j & 1][k], acc2, 0, 0, 0);
            acc3 = __builtin_amdgcn_mfma_f32_16x16x32_bf16(af[3][k], bf[j & 1][k], acc3, 0, 0, 0);
        }
        #pragma unroll
        for (int r = 0; r < 4; r++) {
            sumacc[0][r] += __builtin_amdgcn_exp2f(acc0[r]);
            sumacc[1][r] += __builtin_amdgcn_exp2f(acc1[r]);
            sumacc[2][r] += __builtin_amdgcn_exp2f(acc2[r]);
            sumacc[3][r] += __builtin_amdgcn_exp2f(acc3[r]);
        }
    }

    // per-row combine: reduce 16 column-lanes, atomic into global
    #pragma unroll
    for (int i = 0; i < 4; i++) {
        #pragma unroll
        for (int r = 0; r < 4; r++) {
            float v = sumacc[i][r];
            v += __shfl_xor(v, 1, 64);
            v += __shfl_xor(v, 2, 64);
            v += __shfl_xor(v, 4, 64);
            v += __shfl_xor(v, 8, 64);
            if ((lane & 15) == 0) {
                int row = rowTile * 128 + wr * 64 + i * 16 + q * 4 + r;
                atomicAdd(&sumexp[row], v);
            }
        }
    }
}

// ---------- final: lse, relu, mean -> scalar --------------------------------
__global__ void finalize(const float* __restrict__ sumexp,
                         const float* __restrict__ pos_sim,
                         const float* __restrict__ r_score,
                         float* __restrict__ out) {
    __shared__ float red[4];
    int t = threadIdx.x;
    float acc = 0.0f;
    #pragma unroll
    for (int i = 0; i < 8; i++) {
        int row = t + i * 256;
        float lse  = __log2f(sumexp[row]) * LN2;   // A was pre-scaled by log2e
        float loss = lse - pos_sim[row] + r_score[row] + 1.0f;
        acc += fmaxf(loss, 0.0f);
    }
    #pragma unroll
    for (int m = 1; m <= 32; m <<= 1) acc += __shfl_xor(acc, m, 64);
    if ((t & 63) == 0) red[t >> 6] = acc;
    __syncthreads();
    if (t == 0) out[0] = (red[0] + red[1] + red[2] + red[3]) * (1.0f / (float)B_ROWS);
}

extern "C" void kernel_launch(void* const* d_in, const int* in_sizes, int n_in,
                              void* d_out, int out_size, void* d_ws, size_t ws_size,
                              hipStream_t stream) {
    const float* anchor   = (const float*)d_in[0];
    const float* positive = (const float*)d_in[1];
    const float* negative = (const float*)d_in[2];
    const float* r_score  = (const float*)d_in[3];
    float* out = (float*)d_out;

    char* ws = (char*)d_ws;
    float* sumexp           = (float*)ws;                       // 2048 f32
    float* pos_sim          = (float*)(ws + 8192);              // 2048 f32
    unsigned short* a_bf    = (unsigned short*)(ws + 16384);    // 512 KB
    unsigned short* n_bf    = (unsigned short*)(ws + 16384 + 524288); // 8 MB

    prep<<<1280, 256, 0, stream>>>(anchor, positive, negative, a_bf, n_bf, pos_sim, sumexp);
    fused_gemm_lse<<<1024, 256, 0, stream>>>(a_bf, n_bf, sumexp);
    finalize<<<1, 256, 0, stream>>>(sumexp, pos_sim, r_score, out);
}

// Round 3
// 161.096 us; speedup vs baseline: 1.8436x; 1.8436x over previous
//
#include <hip/hip_runtime.h>
#include <hip/hip_bf16.h>

// SoftmaxLossRScore: mean(relu(logsumexp(A @ Neg^T, axis=1) - rowdot(A,P) + r + 1))
// B=2048, N=32768, D=128. bf16 MFMA fused GEMM+sumexp, no [B,N] materialization.
// A pre-scaled by log2(e) so epilogue is a bare v_exp_f32 (exp2).
// R2: XOR-swizzled LDS chunks (chunk ^= row&7) kill frag-read bank conflicts.
// R5: back to LDS-staged B (R4 post-mortem: register-direct B = 263MB refetch,
//     5x regression). One lever vs R0: B-tile halved to 64x128 (16KB/buf),
//     A staged THROUGH the two B buffers then register-resident, so LDS =
//     32KB/block -> 4 blocks/CU (grid 1024, all resident). Block drains now
//     overlap other blocks' MFMA via TLP. XCD-bijective swizzle: each XCD owns
//     a 1MB B slice + 512KB A = L2-resident.

#define B_ROWS 2048
#define N_NEG  32768
#define DIM    128
#define LOG2E  1.4426950408889634f
#define LN2    0.6931471805599453f

typedef __bf16 bf16x8 __attribute__((ext_vector_type(8)));
typedef float  f32x4  __attribute__((ext_vector_type(4)));

static __device__ inline unsigned short f2bf(float f) {
    union { float f; unsigned u; } v; v.f = f;
    unsigned r = v.u + 0x7FFF + ((v.u >> 16) & 1);   // round-to-nearest-even
    return (unsigned short)(r >> 16);
}

static __device__ inline void load_lds16(const void* g, void* s) {
    __builtin_amdgcn_global_load_lds(
        (const __attribute__((address_space(1))) void*)g,
        (__attribute__((address_space(3))) void*)s,
        16, 0, 0);
}

// ---------- P1 (merged): anchor->bf16*log2e + pos_sim + zero sumexp, neg->bf16
__global__ void prep(const float* __restrict__ anchor,
                     const float* __restrict__ positive,
                     const float* __restrict__ neg,
                     unsigned short* __restrict__ a_bf,
                     unsigned short* __restrict__ n_bf,
                     float* __restrict__ pos_sim,
                     float* __restrict__ sumexp) {
    int t = threadIdx.x;
    if (blockIdx.x < 256) {
        int row = blockIdx.x * 8 + (t >> 5);
        int c4  = (t & 31) * 4;
        const float4 a4 = *(const float4*)(anchor   + row * DIM + c4);
        const float4 p4 = *(const float4*)(positive + row * DIM + c4);
        float dot = a4.x * p4.x + a4.y * p4.y + a4.z * p4.z + a4.w * p4.w;
        ushort4 ab;
        ab.x = f2bf(a4.x * LOG2E); ab.y = f2bf(a4.y * LOG2E);
        ab.z = f2bf(a4.z * LOG2E); ab.w = f2bf(a4.w * LOG2E);
        *(ushort4*)(a_bf + row * DIM + c4) = ab;
        #pragma unroll
        for (int m = 1; m <= 16; m <<= 1) dot += __shfl_xor(dot, m, 64);
        if ((t & 31) == 0) { pos_sim[row] = dot; sumexp[row] = 0.0f; }
    } else {
        int i = (blockIdx.x - 256) * 256 + t;   // float4 index
        #pragma unroll
        for (int k = 0; k < 4; k++) {
            int idx = i + k * (1024 * 256);
            float4 v = *(const float4*)(neg + (size_t)idx * 4);
            ushort4 o;
            o.x = f2bf(v.x); o.y = f2bf(v.y); o.z = f2bf(v.z); o.w = f2bf(v.w);
            *(ushort4*)(n_bf + (size_t)idx * 4) = o;
        }
    }
}

// ---------- main: fused bf16 GEMM + sum(exp2) -------------------------------
// Grid 1024 = 16 row-tiles x 64 chunks (512 cols). Block 256 thr = 4 waves
// (2 row x 2 col). Per t-step: B-tile 64 cols x 128 K staged in one 16KB LDS
// buffer (double-buffered), wave computes 2 j-tiles of 16 cols. A tile
// (128x128) staged once through both buffers, then register-resident af[4][4].
// LDS rows are 256 B; 16B chunk j of row r stored at slot j^(r&7) (swizzle
// applied on the global source address).
#define CHUNK 512
#define TSTEPS (CHUNK / 64)   // 8

__global__ __launch_bounds__(256, 4) void fused_gemm_lse(
        const unsigned short* __restrict__ A,
        const unsigned short* __restrict__ Nb,
        float* __restrict__ sumexp) {
    __shared__ unsigned short lds[16384];   // 32 KB = 2 x 16KB B buffers

    // XCD-bijective swizzle: hw maps bid -> XCD bid%8; give each XCD 8 chunks
    // (1 MB of B, per-XCD-L2-resident) across all 16 rowTiles.
    const int bid  = blockIdx.x;
    const int xcd  = bid & 7;
    const int slot = bid >> 3;                   // 0..127
    const int rowTile = slot & 15;
    const int chunk   = xcd * 8 + (slot >> 4);   // 0..63, 512 cols each

    const int wave = threadIdx.x >> 6, lane = threadIdx.x & 63;
    const int wr = wave >> 1, wc = wave & 1;
    const int q = lane >> 4, c = lane & 15;
    const int lrow = lane >> 4;       // staging: row within 4-row group
    const int lchk = lane & 15;       // staging: 16B chunk within row

    const unsigned short* Ag = A + rowTile * (128 * DIM);
    const unsigned short* Bg = Nb + (size_t)(chunk * CHUNK) * DIM;

    // ---- stage A tile (32 KB) through both buffers, swizzled source ----
    #pragma unroll
    for (int i = 0; i < 8; i++) {
        int off = wave * 4096 + i * 512;            // ushort offset, 4 rows
        int r   = (off >> 7) + lrow;                // absolute row in tile
        int gofs = r * DIM + ((lchk ^ (r & 7)) << 3);
        load_lds16(Ag + gofs, &lds[off]);
    }
    asm volatile("s_waitcnt vmcnt(0)" ::: "memory");
    __syncthreads();

    // swizzled k-step chunk offsets (ushort units); row&7 == c&7 for all our
    // fragment rows (row = 16*m + c), so this is t/j-invariant.
    int swz[4];
    #pragma unroll
    for (int k = 0; k < 4; k++) swz[k] = (((k * 4 + q) ^ (c & 7)) << 3);

    // preload A fragments: wave rows wr*64..+64, 4 subtiles x 4 k-steps
    bf16x8 af[4][4];
    #pragma unroll
    for (int i = 0; i < 4; i++) {
        int row = wr * 64 + i * 16 + c;
        #pragma unroll
        for (int k = 0; k < 4; k++)
            af[i][k] = *(const bf16x8*)&lds[row * DIM + swz[k]];
    }
    __syncthreads();   // all af reads done; buffers free for B

    // ---- stage B(0) -> buffer 0 ----
    #pragma unroll
    for (int i = 0; i < 4; i++) {
        int off = wave * 2048 + i * 512;            // 16 rows/wave, 4 rows/iter
        int r   = (off >> 7) + lrow;                // 0..63
        int gofs = r * DIM + ((lchk ^ (r & 7)) << 3);
        load_lds16(Bg + gofs, &lds[off]);
    }
    asm volatile("s_waitcnt vmcnt(0)" ::: "memory");
    __syncthreads();

    const f32x4 zero4 = {0.f, 0.f, 0.f, 0.f};
    f32x4 sumacc[4] = {zero4, zero4, zero4, zero4};

    for (int t = 0; t < TSTEPS; t++) {
        const int curb = (t & 1) * 8192;            // current buffer base
        const int nxtb = 8192 - curb;
        if (t + 1 < TSTEPS) {                       // async prefetch B(t+1)
            const unsigned short* Bn = Bg + (size_t)(t + 1) * 64 * DIM;
            #pragma unroll
            for (int i = 0; i < 4; i++) {
                int off = wave * 2048 + i * 512;
                int r   = (off >> 7) + lrow;
                int gofs = r * DIM + ((lchk ^ (r & 7)) << 3);
                load_lds16(Bn + gofs, &lds[nxtb + off]);
            }
        }
        #pragma unroll
        for (int j = 0; j < 2; j++) {               // wave cols = wc*32 + j*16
            int brow = wc * 32 + j * 16 + c;
            bf16x8 bf[4];
            #pragma unroll
            for (int k = 0; k < 4; k++)
                bf[k] = *(const bf16x8*)&lds[curb + brow * DIM + swz[k]];
            #pragma unroll
            for (int i = 0; i < 4; i++) {
                f32x4 acc = __builtin_amdgcn_mfma_f32_16x16x32_bf16(af[i][0], bf[0], zero4, 0, 0, 0);
                acc = __builtin_amdgcn_mfma_f32_16x16x32_bf16(af[i][1], bf[1], acc, 0, 0, 0);
                acc = __builtin_amdgcn_mfma_f32_16x16x32_bf16(af[i][2], bf[2], acc, 0, 0, 0);
                acc = __builtin_amdgcn_mfma_f32_16x16x32_bf16(af[i][3], bf[3], acc, 0, 0, 0);
                sumacc[i][0] += __builtin_amdgcn_exp2f(acc[0]);
                sumacc[i][1] += __builtin_amdgcn_exp2f(acc[1]);
                sumacc[i][2] += __builtin_amdgcn_exp2f(acc[2]);
                sumacc[i][3] += __builtin_amdgcn_exp2f(acc[3]);
            }
        }
        if (t + 1 < TSTEPS) {
            asm volatile("s_waitcnt vmcnt(0)" ::: "memory");
            __syncthreads();
        }
    }

    // per-row combine: reduce 16 column-lanes, atomic into global
    #pragma unroll
    for (int i = 0; i < 4; i++) {
        #pragma unroll
        for (int r = 0; r < 4; r++) {
            float v = sumacc[i][r];
            v += __shfl_xor(v, 1, 64);
            v += __shfl_xor(v, 2, 64);
            v += __shfl_xor(v, 4, 64);
            v += __shfl_xor(v, 8, 64);
            if ((lane & 15) == 0) {
                int row = rowTile * 128 + wr * 64 + i * 16 + q * 4 + r;
                atomicAdd(&sumexp[row], v);
            }
        }
    }
}

// ---------- final: lse, relu, mean -> scalar --------------------------------
__global__ void finalize(const float* __restrict__ sumexp,
                         const float* __restrict__ pos_sim,
                         const float* __restrict__ r_score,
                         float* __restrict__ out) {
    __shared__ float red[4];
    int t = threadIdx.x;
    float acc = 0.0f;
    #pragma unroll
    for (int i = 0; i < 8; i++) {
        int row = t + i * 256;
        float lse  = __log2f(sumexp[row]) * LN2;   // A was pre-scaled by log2e
        float loss = lse - pos_sim[row] + r_score[row] + 1.0f;
        acc += fmaxf(loss, 0.0f);
    }
    #pragma unroll
    for (int m = 1; m <= 32; m <<= 1) acc += __shfl_xor(acc, m, 64);
    if ((t & 63) == 0) red[t >> 6] = acc;
    __syncthreads();
    if (t == 0) out[0] = (red[0] + red[1] + red[2] + red[3]) * (1.0f / (float)B_ROWS);
}

extern "C" void kernel_launch(void* const* d_in, const int* in_sizes, int n_in,
                              void* d_out, int out_size, void* d_ws, size_t ws_size,
                              hipStream_t stream) {
    const float* anchor   = (const float*)d_in[0];
    const float* positive = (const float*)d_in[1];
    const float* negative = (const float*)d_in[2];
    const float* r_score  = (const float*)d_in[3];
    float* out = (float*)d_out;

    char* ws = (char*)d_ws;
    float* sumexp           = (float*)ws;                       // 2048 f32
    float* pos_sim          = (float*)(ws + 8192);              // 2048 f32
    unsigned short* a_bf    = (unsigned short*)(ws + 16384);    // 512 KB
    unsigned short* n_bf    = (unsigned short*)(ws + 16384 + 524288); // 8 MB

    prep<<<1280, 256, 0, stream>>>(anchor, positive, negative, a_bf, n_bf, pos_sim, sumexp);
    fused_gemm_lse<<<1024, 256, 0, stream>>>(a_bf, n_bf, sumexp);
    finalize<<<1, 256, 0, stream>>>(sumexp, pos_sim, r_score, out);
}

// Round 4
// 95.288 us; speedup vs baseline: 3.1168x; 1.6906x over previous
//
#include <hip/hip_runtime.h>
#include <hip/hip_bf16.h>

// SoftmaxLossRScore: mean(relu(logsumexp(A @ Neg^T, axis=1) - rowdot(A,P) + r + 1))
// B=2048, N=32768, D=128. bf16 MFMA fused GEMM+sumexp, no [B,N] materialization.
// A pre-scaled by log2(e) so epilogue is a bare v_exp_f32 (exp2).
// R2: XOR-swizzled LDS chunks (chunk ^= row&7) kill frag-read bank conflicts.
// R6: restore R0 geometry VERBATIM (grid 512, chunk 1024, 64KB LDS, natural bid
//     order -- R4/R5 post-mortems: every geometry change regressed; R0's
//     consecutive-bid dispatch gives L2/L3 temporal locality for free).
//     ONE change: counted-vmcnt pipeline (T3+T4). LDS = 4-slot ring of 16KB
//     half-tiles; next tile's 8 loads stay IN FLIGHT across raw s_barriers
//     (vmcnt(8) at loop top, never 0 until the last tile). No __syncthreads in
//     the loop (its implicit vmcnt(0) is the m97-ceiling stall).

#define B_ROWS 2048
#define N_NEG  32768
#define DIM    128
#define LOG2E  1.4426950408889634f
#define LN2    0.6931471805599453f

typedef __bf16 bf16x8 __attribute__((ext_vector_type(8)));
typedef float  f32x4  __attribute__((ext_vector_type(4)));

static __device__ inline unsigned short f2bf(float f) {
    union { float f; unsigned u; } v; v.f = f;
    unsigned r = v.u + 0x7FFF + ((v.u >> 16) & 1);   // round-to-nearest-even
    return (unsigned short)(r >> 16);
}

static __device__ inline void load_lds16(const void* g, void* s) {
    __builtin_amdgcn_global_load_lds(
        (const __attribute__((address_space(1))) void*)g,
        (__attribute__((address_space(3))) void*)s,
        16, 0, 0);
}

// ---------- P1 (merged): anchor->bf16*log2e + pos_sim + zero sumexp, neg->bf16
__global__ void prep(const float* __restrict__ anchor,
                     const float* __restrict__ positive,
                     const float* __restrict__ neg,
                     unsigned short* __restrict__ a_bf,
                     unsigned short* __restrict__ n_bf,
                     float* __restrict__ pos_sim,
                     float* __restrict__ sumexp) {
    int t = threadIdx.x;
    if (blockIdx.x < 256) {
        int row = blockIdx.x * 8 + (t >> 5);
        int c4  = (t & 31) * 4;
        const float4 a4 = *(const float4*)(anchor   + row * DIM + c4);
        const float4 p4 = *(const float4*)(positive + row * DIM + c4);
        float dot = a4.x * p4.x + a4.y * p4.y + a4.z * p4.z + a4.w * p4.w;
        ushort4 ab;
        ab.x = f2bf(a4.x * LOG2E); ab.y = f2bf(a4.y * LOG2E);
        ab.z = f2bf(a4.z * LOG2E); ab.w = f2bf(a4.w * LOG2E);
        *(ushort4*)(a_bf + row * DIM + c4) = ab;
        #pragma unroll
        for (int m = 1; m <= 16; m <<= 1) dot += __shfl_xor(dot, m, 64);
        if ((t & 31) == 0) { pos_sim[row] = dot; sumexp[row] = 0.0f; }
    } else {
        int i = (blockIdx.x - 256) * 256 + t;   // float4 index
        #pragma unroll
        for (int k = 0; k < 4; k++) {
            int idx = i + k * (1024 * 256);
            float4 v = *(const float4*)(neg + (size_t)idx * 4);
            ushort4 o;
            o.x = f2bf(v.x); o.y = f2bf(v.y); o.z = f2bf(v.z); o.w = f2bf(v.w);
            *(ushort4*)(n_bf + (size_t)idx * 4) = o;
        }
    }
}

// ---------- main: fused bf16 GEMM + sum(exp2) -------------------------------
// Grid 512 = 16 row-tiles x 32 N-chunks. Block 256 thr = 4 waves (2x2).
// Block tile 128 rows x 1024 cols, inner BN=128. A-frags register-resident.
// LDS 64 KB = ring of 4 slots x 16 KB (64 B-rows each). Tile t occupies slots
// {(2t+2)&3, (2t+3)&3}; wave (wr,wc) reads half wc of its tile. Staging: wave
// w loads 32 rows of half (w>>1) -- 8 x global_load_lds(16B) per tile.
// LDS rows are 256 B; 16B chunk j of row r holds global chunk j^(r&7)
// (swizzle applied on the global source address; DMA dest stays linear).
#define CHUNK 1024
#define TSTEPS (CHUNK / 128)   // 8

__global__ __launch_bounds__(256, 2) void fused_gemm_lse(
        const unsigned short* __restrict__ A,
        const unsigned short* __restrict__ Nb,
        float* __restrict__ sumexp) {
    __shared__ unsigned short lds[4 * 8192];   // 64 KB ring

    const int bid     = blockIdx.x;
    const int rowTile = bid & 15;
    const int chunk   = bid >> 4;
    const int wave = threadIdx.x >> 6, lane = threadIdx.x & 63;
    const int wr = wave >> 1, wc = wave & 1;
    const int q = lane >> 4, c = lane & 15;
    const int lrow = lane >> 4;       // staging: row within 4-row group
    const int lchk = lane & 15;       // staging: 16B chunk within row

    const unsigned short* Ag = A + rowTile * (128 * DIM);
    const unsigned short* Bg = Nb + (size_t)(chunk * CHUNK) * DIM;

// stage one 128-row tile at gbase into the ring slots of tile index (tt):
// half h -> slot (2*tt+2+h)&3. Wave w stages rows (w&1)*32..+31 of half w>>1.
// LDS dest is wave-uniform (DMA writes base + lane*16); global src is per-lane
// with the XOR swizzle folded in.
#define STAGE_TILE(gbase, tt)                                                  \
    {                                                                          \
        const int h_ = wave >> 1;                                              \
        const int s_ = (2 * (tt) + 2 + h_) & 3;                                \
        _Pragma("unroll")                                                      \
        for (int i_ = 0; i_ < 8; i_++) {                                       \
            int rloc_ = (wave & 1) * 32 + i_ * 4;       /* uniform base row */ \
            int rg_   = h_ * 64 + rloc_ + lrow;         /* per-lane tile row */\
            int gofs_ = rg_ * DIM + ((lchk ^ (rg_ & 7)) << 3);                 \
            load_lds16((gbase) + gofs_, &lds[s_ * 8192 + rloc_ * DIM]);        \
        }                                                                      \
    }

    // ---- prologue: A -> slots {0,1}, B(0) -> slots {2,3} ----
    STAGE_TILE(Ag, -1);                    // slots h (= {0,1})
    STAGE_TILE(Bg, 0);                     // slots {2,3}
    asm volatile("s_waitcnt vmcnt(8)" ::: "memory");   // A landed, B0 in flight
    __builtin_amdgcn_s_barrier();

    // swizzled k-step chunk offsets (ushort units); fragment rows are == c
    // mod 8 everywhere, so this is invariant across t/j/i.
    int swz[4];
    #pragma unroll
    for (int k = 0; k < 4; k++) swz[k] = (((k * 4 + q) ^ (c & 7)) << 3);

    // preload A fragments: wave rows wr*64..+64 live in slot wr
    bf16x8 af[4][4];
    #pragma unroll
    for (int i = 0; i < 4; i++) {
        int row = i * 16 + c;              // row within the 64-row half
        #pragma unroll
        for (int k = 0; k < 4; k++)
            af[i][k] = *(const bf16x8*)&lds[wr * 8192 + row * DIM + swz[k]];
    }
    asm volatile("s_waitcnt lgkmcnt(0)" ::: "memory");
    __builtin_amdgcn_s_barrier();          // af reads done; slots {0,1} free

    STAGE_TILE(Bg + 128 * DIM, 1);         // B(1) -> slots {0,1}

    const f32x4 zero4 = {0.f, 0.f, 0.f, 0.f};
    f32x4 sumacc[4] = {zero4, zero4, zero4, zero4};

    for (int t = 0; t < TSTEPS; t++) {
        // wait: current tile's loads landed; next tile's 8 stay in flight
        if (t < TSTEPS - 1) asm volatile("s_waitcnt vmcnt(8)" ::: "memory");
        else                asm volatile("s_waitcnt vmcnt(0)" ::: "memory");
        __builtin_amdgcn_s_barrier();

        const int sb = (2 * t + 2 + wc) & 3;   // this wave's B half-slot
        #pragma unroll
        for (int j = 0; j < 4; j++) {          // 4 j-tiles of 16 cols
            int brow = j * 16 + c;             // row within the half
            bf16x8 bf[4];
            #pragma unroll
            for (int k = 0; k < 4; k++)
                bf[k] = *(const bf16x8*)&lds[sb * 8192 + brow * DIM + swz[k]];
            #pragma unroll
            for (int i = 0; i < 4; i++) {
                f32x4 acc = __builtin_amdgcn_mfma_f32_16x16x32_bf16(af[i][0], bf[0], zero4, 0, 0, 0);
                acc = __builtin_amdgcn_mfma_f32_16x16x32_bf16(af[i][1], bf[1], acc, 0, 0, 0);
                acc = __builtin_amdgcn_mfma_f32_16x16x32_bf16(af[i][2], bf[2], acc, 0, 0, 0);
                acc = __builtin_amdgcn_mfma_f32_16x16x32_bf16(af[i][3], bf[3], acc, 0, 0, 0);
                sumacc[i][0] += __builtin_amdgcn_exp2f(acc[0]);
                sumacc[i][1] += __builtin_amdgcn_exp2f(acc[1]);
                sumacc[i][2] += __builtin_amdgcn_exp2f(acc[2]);
                sumacc[i][3] += __builtin_amdgcn_exp2f(acc[3]);
            }
        }
        asm volatile("s_waitcnt lgkmcnt(0)" ::: "memory");
        __builtin_amdgcn_s_barrier();          // all reads of tile t done
        if (t + 2 < TSTEPS)                    // overwrite tile t's slots
            STAGE_TILE(Bg + (size_t)(t + 2) * 128 * DIM, t + 2);
    }
#undef STAGE_TILE

    // per-row combine: reduce 16 column-lanes, atomic into global
    #pragma unroll
    for (int i = 0; i < 4; i++) {
        #pragma unroll
        for (int r = 0; r < 4; r++) {
            float v = sumacc[i][r];
            v += __shfl_xor(v, 1, 64);
            v += __shfl_xor(v, 2, 64);
            v += __shfl_xor(v, 4, 64);
            v += __shfl_xor(v, 8, 64);
            if ((lane & 15) == 0) {
                int row = rowTile * 128 + wr * 64 + i * 16 + q * 4 + r;
                atomicAdd(&sumexp[row], v);
            }
        }
    }
}

// ---------- final: lse, relu, mean -> scalar --------------------------------
__global__ void finalize(const float* __restrict__ sumexp,
                         const float* __restrict__ pos_sim,
                         const float* __restrict__ r_score,
                         float* __restrict__ out) {
    __shared__ float red[4];
    int t = threadIdx.x;
    float acc = 0.0f;
    #pragma unroll
    for (int i = 0; i < 8; i++) {
        int row = t + i * 256;
        float lse  = __log2f(sumexp[row]) * LN2;   // A was pre-scaled by log2e
        float loss = lse - pos_sim[row] + r_score[row] + 1.0f;
        acc += fmaxf(loss, 0.0f);
    }
    #pragma unroll
    for (int m = 1; m <= 32; m <<= 1) acc += __shfl_xor(acc, m, 64);
    if ((t & 63) == 0) red[t >> 6] = acc;
    __syncthreads();
    if (t == 0) out[0] = (red[0] + red[1] + red[2] + red[3]) * (1.0f / (float)B_ROWS);
}

extern "C" void kernel_launch(void* const* d_in, const int* in_sizes, int n_in,
                              void* d_out, int out_size, void* d_ws, size_t ws_size,
                              hipStream_t stream) {
    const float* anchor   = (const float*)d_in[0];
    const float* positive = (const float*)d_in[1];
    const float* negative = (const float*)d_in[2];
    const float* r_score  = (const float*)d_in[3];
    float* out = (float*)d_out;

    char* ws = (char*)d_ws;
    float* sumexp           = (float*)ws;                       // 2048 f32
    float* pos_sim          = (float*)(ws + 8192);              // 2048 f32
    unsigned short* a_bf    = (unsigned short*)(ws + 16384);    // 512 KB
    unsigned short* n_bf    = (unsigned short*)(ws + 16384 + 524288); // 8 MB

    prep<<<1280, 256, 0, stream>>>(anchor, positive, negative, a_bf, n_bf, pos_sim, sumexp);
    fused_gemm_lse<<<512, 256, 0, stream>>>(a_bf, n_bf, sumexp);
    finalize<<<1, 256, 0, stream>>>(sumexp, pos_sim, r_score, out);
}